// Round 15
// baseline (5274.871 us; speedup 1.0000x reference)
//
#include <hip/hip_runtime.h>

// ---------------------------------------------------------------------------
// SSM evaluator, MFMA version, R15 = R12 (best, 2642us) + 2 blocks/CU.
// R11-R14 showed AGPR parking inserts per-use accvgpr_read copies (net loss).
// R12's limiter: LDS 161KB -> 1 block/CU -> 1 wave/SIMD -> nothing hides
// spill-reload/ds_read latency. Fix: drop loMS/loGP LDS buffers (96KB) and
// read MS-lo/GP-lo B-fragments directly from global (per-XCD demand 3MB < 4MB
// L2 -> resident). LDS ~61KB <= 64KB -> 2 blocks/CU, 2 waves/SIMD; the
// co-resident block hides the latencies. Otherwise byte-identical to R12.
// ---------------------------------------------------------------------------

typedef _Float16 f16x8 __attribute__((ext_vector_type(8)));
typedef _Float16 f16x4 __attribute__((ext_vector_type(4)));
typedef float    f32x4 __attribute__((ext_vector_type(4)));
typedef unsigned short u16;
typedef unsigned long long u64;

#define MFMA16(a,b,c) __builtin_amdgcn_mfma_f32_16x16x32_f16((a),(b),(c),0,0,0)
#define FENCE() __builtin_amdgcn_sched_barrier(0)

namespace {
constexpr int S = 128;
constexpr long FRAC_OFF = 25165824L;
constexpr long XLP_OFF  = 33554432L;
constexpr long ZLP_OFF  = 58720256L;
constexpr float HLOG2PI = 0.91893853320467274f;
constexpr float INVLO   = 1.0f / 2048.0f;

// ws arena offsets (u16 elements). [col][k] layout, hi then lo.
constexpr int C1HI = 0,      C1LO = 12288;   // [128][96]
constexpr int GPHI = 24576,  GPLO = 40960;   // [128][128]
constexpr int WZHI = 57344,  WZLO = 61440;   // [64][64]
constexpr int SCHI = 65536,  SCLO = 69632;   // [64][64]
constexpr int W1B  = 73728;                  // +f*16384 hi, +8192 lo [128][64]
constexpr int MSB  = 106496;                 // +f*32768 hi, +16384 lo [128][128]
constexpr int E1HI = 172032, E1LO = 180224;  // [128][64]
constexpr int E2HI = 188416, E2LO = 192512;  // [32][128]
constexpr int XHI  = 196608, XLO  = 458752;  // input split planes
}

__device__ __forceinline__ float sigm(float x)      { return 1.0f / (1.0f + __expf(-x)); }
__device__ __forceinline__ float softplusf_(float x){ return fmaxf(x, 0.f) + __logf(1.f + __expf(-fabsf(x))); }
__device__ __forceinline__ float logsigm(float x)   { return fminf(x, 0.f) - __logf(1.f + __expf(-fabsf(x))); }

__device__ __forceinline__ void split2(float v, _Float16& hi, _Float16& lo) {
    hi = (_Float16)v;
    lo = (_Float16)((v - (float)hi) * 2048.0f);
}

__device__ __forceinline__ f16x8 rdA(const u16* t, int row, int k, int strideEls, int swm) {
    int byte = ((row * strideEls + k) * 2) ^ ((row & swm) << 4);
    return *(const f16x8*)((const char*)t + byte);
}
__device__ __forceinline__ f16x8 ldB(const u16* wa, int base, int col, int K, int koff) {
    return *(const f16x8*)(wa + base + col * K + koff);
}

// single-col-tile dual-row-tile job, both planes in regs (Wz/Wsc etc.)
template<int NKS, int STRIDE, int SWM>
__device__ __forceinline__ void mmDual(const u16* Th, const u16* Tl, int lnc, int kf,
                                       const f16x8 (&wh)[NKS], const f16x8 (&wl)[NKS],
                                       float bias, f32x4& H0, f32x4& L0, f32x4& H1, f32x4& L1)
{
    H0 = (f32x4){bias, bias, bias, bias}; H1 = H0;
    L0 = (f32x4){0.f, 0.f, 0.f, 0.f};     L1 = L0;
#pragma unroll
    for (int ks = 0; ks < NKS; ++ks) {
        int k = ks * 32 + kf;
        f16x8 a0h = rdA(Th, lnc,      k, STRIDE, SWM);
        f16x8 a0l = rdA(Tl, lnc,      k, STRIDE, SWM);
        f16x8 a1h = rdA(Th, 16 + lnc, k, STRIDE, SWM);
        f16x8 a1l = rdA(Tl, 16 + lnc, k, STRIDE, SWM);
        H0 = MFMA16(a0h, wh[ks], H0); L0 = MFMA16(a0h, wl[ks], L0); L0 = MFMA16(a0l, wh[ks], L0);
        H1 = MFMA16(a1h, wh[ks], H1); L1 = MFMA16(a1h, wl[ks], L1); L1 = MFMA16(a1l, wh[ks], L1);
    }
}

template<bool RELU>
__device__ __forceinline__ void stAct(f32x4 H, f32x4 L, int rt, int lng, int col,
                                      u16* th, u16* tl, int strideEls, int swm)
{
#pragma unroll
    for (int q = 0; q < 4; ++q) {
        int row = rt * 16 + lng * 4 + q;
        float v = H[q] + L[q] * INVLO;
        if (RELU) v = fmaxf(v, 0.f);
        _Float16 hi, lo; split2(v, hi, lo);
        int byte = ((row * strideEls + col) * 2) ^ ((row & swm) << 4);
        *(_Float16*)((char*)th + byte) = hi;
        *(_Float16*)((char*)tl + byte) = lo;
    }
}
__device__ __forceinline__ void stScr(f32x4 H, f32x4 L, int rt, int lng, int col,
                                      float* s, int strideEls)
{
#pragma unroll
    for (int q = 0; q < 4; ++q) {
        int row = rt * 16 + lng * 4 + q;
        int byte = ((row * strideEls + col) * 4) ^ ((row & 7) << 4);
        *(float*)((char*)s + byte) = H[q] + L[q] * INVLO;
    }
}
__device__ __forceinline__ f32x4 rdS4(const float* s, int strideEls, int row, int c) {
    int byte = ((row * strideEls + c) * 4) ^ ((row & 7) << 4);
    return *(const f32x4*)((const char*)s + byte);
}
__device__ __forceinline__ float rdS1(const float* s, int strideEls, int row, int c) {
    int byte = ((row * strideEls + c) * 4) ^ ((row & 7) << 4);
    return *(const float*)((const char*)s + byte);
}
__device__ __forceinline__ void wrS4(float* s, int strideEls, int row, int c, f32x4 v) {
    int byte = ((row * strideEls + c) * 4) ^ ((row & 7) << 4);
    *(f32x4*)((char*)s + byte) = v;
}
__device__ __forceinline__ void wrF16x4(u16* t, int strideEls, int row, int c, f16x4 v) {
    int byte = ((row * strideEls + c) * 2) ^ ((row & 7) << 4);
    *(f16x4*)((char*)t + byte) = v;
}
__device__ __forceinline__ f16x4 rdF16x4(const u16* t, int strideEls, int row, int c) {
    int byte = ((row * strideEls + c) * 2) ^ ((row & 7) << 4);
    return *(const f16x4*)((const char*)t + byte);
}

// --- prep: masked/stacked/transposed/split weights + split input ------------
__global__ void prep_kernel(const float* __restrict__ input,
                            const float* __restrict__ Wxh, const float* __restrict__ Wzh,
                            const float* __restrict__ Wg,  const float* __restrict__ Wp,
                            const float* __restrict__ Wz,  const float* __restrict__ Wsc,
                            const float* __restrict__ W1,  const float* __restrict__ Wm,
                            const float* __restrict__ Ws_, const float* __restrict__ We1,
                            const float* __restrict__ We2, u16* __restrict__ wa)
{
    int idx = blockIdx.x * 256 + threadIdx.x;
    if (idx < 98304) {
        int hio = 0, loo = 0; float v = 0.f;
        int i = idx;
        if (i < 12288) {
            int col = i / 96, k = i % 96;
            v = (k < 32) ? Wxh[k * 128 + col] : Wzh[(k - 32) * 128 + col];
            hio = C1HI + i; loo = C1LO + i;
        } else if (i < 28672) { int j = i - 12288;
            int col = j >> 7, k = j & 127;
            v = (col < 64) ? Wg[k * 64 + col] : Wp[k * 64 + col - 64];
            hio = GPHI + j; loo = GPLO + j;
        } else if (i < 32768) { int j = i - 28672;
            int col = j >> 6, k = j & 63; v = Wz[k * 64 + col];
            hio = WZHI + j; loo = WZLO + j;
        } else if (i < 36864) { int j = i - 32768;
            int col = j >> 6, k = j & 63; v = Wsc[k * 64 + col];
            hio = SCHI + j; loo = SCLO + j;
        } else if (i < 53248) { int j = i - 36864;
            int f = j >> 13, jj = j & 8191;
            int col = jj >> 6, k = jj & 63;
            v = W1[(f * 64 + k) * 128 + col] * (((col % 63) >= k) ? 1.f : 0.f);
            hio = W1B + f * 16384 + jj; loo = hio + 8192;
        } else if (i < 86016) { int j = i - 53248;
            int f = j >> 14, jj = j & 16383;
            int col = jj >> 7, k = jj & 127;
            if (col < 64) v = Wm[(f * 128 + k) * 64 + col] * (((k % 63) < col) ? 1.f : 0.f);
            else { int c = col - 64;
                   v = Ws_[(f * 128 + k) * 64 + c]         * (((k % 63) < c)   ? 1.f : 0.f); }
            hio = MSB + f * 32768 + jj; loo = hio + 16384;
        } else if (i < 94208) { int j = i - 86016;
            int col = j >> 6, k = j & 63; v = We1[k * 128 + col];
            hio = E1HI + j; loo = E1LO + j;
        } else { int j = i - 94208;
            int col = j >> 7, k = j & 127; v = We2[k * 32 + col];
            hio = E2HI + j; loo = E2LO + j;
        }
        _Float16 hi, lo; split2(v, hi, lo);
        wa[hio] = __builtin_bit_cast(u16, hi);
        wa[loo] = __builtin_bit_cast(u16, lo);
    } else {
        int j = idx - 98304;
        if (j < 262144) {
            float v = input[j];
            _Float16 hi, lo; split2(v, hi, lo);
            wa[XHI + j] = __builtin_bit_cast(u16, hi);
            wa[XLO + j] = __builtin_bit_cast(u16, lo);
        }
    }
}

// --- main scan kernel -------------------------------------------------------
__global__ __launch_bounds__(256, 2)
void ssm_mfma_kernel(const float* __restrict__ eps, const float* __restrict__ u,
                     const float* __restrict__ bh,  const float* __restrict__ bg,
                     const float* __restrict__ bp,  const float* __restrict__ bz,
                     const float* __restrict__ bsc, const float* __restrict__ b1,
                     const float* __restrict__ bm,  const float* __restrict__ bs,
                     const float* __restrict__ be1, const float* __restrict__ be2,
                     const u16* __restrict__ wa, float* __restrict__ out)
{
    __shared__ u16 tXh[32 * 32],  tXl[32 * 32];
    __shared__ u16 tZh[32 * 64],  tZl[32 * 64];
    __shared__ u16 tHh[32 * 128], tHl[32 * 128];
    __shared__ u16 tPh[32 * 64],  tPl[32 * 64];
    __shared__ float scrB[32 * 128];               // scratch; cols 64-127 double as loc
    __shared__ float scrZ[32 * 64];
    __shared__ float lpS[32][9];
    // (no loMS/loGP: MS-lo and GP-lo read directly from global/L2 -> ~61KB LDS)

    const int tid = threadIdx.x;
    const int ln  = tid & 63, w = tid >> 6;        // wave 0..3
    const int lnc = ln & 15, lng = ln >> 4;
    const int r0  = blockIdx.x * 32, b0 = r0 & 63;
    const int kf  = lng * 8;
    const int ct0   = w * 32 + lnc;                // first col-tile (128-col mats)
    const int colz  = w * 16 + lnc;                // Wz AND Wsc tile
    const int colE2 = (w & 1) * 16 + lnc;          // E2 col
    const int khE2  = w >> 1;                      // E2 k-half (64 k each)
    const int crow  = tid >> 3, cc = (tid & 7) * 8;       // C-phase: 8 cols/thread
    const int erow  = tid & 31, cg = (tid >> 5) * 4;      // C4: 4 cols/thread

    // ---- one-time: weight tiles -> registers (hi planes + small lo planes) ----
    f16x8 wC1h[2][3], wC1l[2][3];        // 48
    f16x8 wGPh[2][4];                    // 32 (lo from global)
    f16x8 wWZh[2], wWZl[2], wSCh[2], wSCl[2];   // 32
    f16x8 wW1h[2][2][2], wW1l[2][2][2];  // 64
    f16x8 wMSh[2][2][4];                 // 64 (lo from global)
    f16x8 wE1h[2][2], wE1l[2][2];        // 32
    f16x8 wE2h[2], wE2l[2];              // 16
#pragma unroll
    for (int j = 0; j < 2; ++j) {
        int colj = ct0 + j * 16;
#pragma unroll
        for (int ks = 0; ks < 3; ++ks) {
            wC1h[j][ks] = ldB(wa, C1HI, colj, 96, ks * 32 + kf);
            wC1l[j][ks] = ldB(wa, C1LO, colj, 96, ks * 32 + kf);
        }
#pragma unroll
        for (int ks = 0; ks < 4; ++ks)
            wGPh[j][ks] = ldB(wa, GPHI, colj, 128, ks * 32 + kf);
#pragma unroll
        for (int ks = 0; ks < 2; ++ks) {
            wE1h[j][ks] = ldB(wa, E1HI, colj, 64, ks * 32 + kf);
            wE1l[j][ks] = ldB(wa, E1LO, colj, 64, ks * 32 + kf);
        }
#pragma unroll
        for (int f = 0; f < 2; ++f) {
#pragma unroll
            for (int ks = 0; ks < 2; ++ks) {
                wW1h[f][j][ks] = ldB(wa, W1B + f * 16384,        colj, 64, ks * 32 + kf);
                wW1l[f][j][ks] = ldB(wa, W1B + f * 16384 + 8192, colj, 64, ks * 32 + kf);
            }
#pragma unroll
            for (int ks = 0; ks < 4; ++ks)
                wMSh[f][j][ks] = ldB(wa, MSB + f * 32768, colj, 128, ks * 32 + kf);
        }
    }
#pragma unroll
    for (int ks = 0; ks < 2; ++ks) {
        wWZh[ks] = ldB(wa, WZHI, colz, 64, ks * 32 + kf);
        wWZl[ks] = ldB(wa, WZLO, colz, 64, ks * 32 + kf);
        wSCh[ks] = ldB(wa, SCHI, colz, 64, ks * 32 + kf);
        wSCl[ks] = ldB(wa, SCLO, colz, 64, ks * 32 + kf);
        wE2h[ks] = ldB(wa, E2HI, colE2, 128, khE2 * 64 + ks * 32 + kf);
        wE2l[ks] = ldB(wa, E2LO, colE2, 128, khE2 * 64 + ks * 32 + kf);
    }

    // biases
    float bhv[2], bGPv[2], bW1v[2][2], bMSv[2][2], bE1v[2];
#pragma unroll
    for (int j = 0; j < 2; ++j) {
        int colj = ct0 + j * 16;
        bhv[j]  = bh[colj];
        bGPv[j] = (colj < 64) ? bg[colj] : bp[colj - 64];
        bE1v[j] = be1[colj];
#pragma unroll
        for (int f = 0; f < 2; ++f) {
            bW1v[f][j] = b1[f * 128 + colj];
            bMSv[f][j] = (colj < 64) ? bm[f * 64 + colj] : bs[f * 64 + colj - 64];
        }
    }
    const float bzv  = bz[colz];
    const float bscv = bsc[colz];
    const float bE2v = (khE2 == 0) ? be2[colE2] : 0.f;

    // init z=0, stage x(t=0)
    for (int i = tid; i < 32 * 64; i += 256) { tZh[i] = 0; tZl[i] = 0; }
    {
        int rr = tid >> 3, d4 = (tid & 7) * 4;
        int ge = (b0 + rr) * 32 + d4;
        u64 xh = *(const u64*)(wa + XHI + ge);
        u64 xl = *(const u64*)(wa + XLO + ge);
        int byte = (rr * 64 + d4 * 2) ^ ((rr & 3) << 4);
        *(u64*)((char*)tXh + byte) = xh;
        *(u64*)((char*)tXl + byte) = xl;
    }
    FENCE();
    __syncthreads();
    FENCE();

    for (int t = 0; t < S; ++t) {
        f32x4 epsA, epsB;   // loaded in C1, consumed in C2

        // ---- PH1: h = relu([x,z]@C1 + bh) (2 ct) ; zwz = z@Wz (1 ct) ----
        {
            f32x4 H[2], L[2], H1[2], L1[2];
#pragma unroll
            for (int j = 0; j < 2; ++j) {
                H[j]  = (f32x4){bhv[j], bhv[j], bhv[j], bhv[j]};
                H1[j] = H[j];
                L[j]  = (f32x4){0.f, 0.f, 0.f, 0.f};
                L1[j] = L[j];
            }
#pragma unroll
            for (int ks = 0; ks < 3; ++ks) {
                f16x8 a0h, a0l, a1h, a1l;
                if (ks == 0) {
                    a0h = rdA(tXh, lnc, kf, 32, 3);      a0l = rdA(tXl, lnc, kf, 32, 3);
                    a1h = rdA(tXh, 16 + lnc, kf, 32, 3); a1l = rdA(tXl, 16 + lnc, kf, 32, 3);
                } else {
                    int k = (ks - 1) * 32 + kf;
                    a0h = rdA(tZh, lnc, k, 64, 7);       a0l = rdA(tZl, lnc, k, 64, 7);
                    a1h = rdA(tZh, 16 + lnc, k, 64, 7);  a1l = rdA(tZl, 16 + lnc, k, 64, 7);
                }
#pragma unroll
                for (int j = 0; j < 2; ++j) {
                    H[j]  = MFMA16(a0h, wC1h[j][ks], H[j]);  L[j]  = MFMA16(a0h, wC1l[j][ks], L[j]);  L[j]  = MFMA16(a0l, wC1h[j][ks], L[j]);
                    H1[j] = MFMA16(a1h, wC1h[j][ks], H1[j]); L1[j] = MFMA16(a1h, wC1l[j][ks], L1[j]); L1[j] = MFMA16(a1l, wC1h[j][ks], L1[j]);
                }
            }
#pragma unroll
            for (int j = 0; j < 2; ++j) {
                stAct<true>(H[j],  L[j],  0, lng, ct0 + j * 16, tHh, tHl, 128, 7);
                stAct<true>(H1[j], L1[j], 1, lng, ct0 + j * 16, tHh, tHl, 128, 7);
            }
        }
        {
            f32x4 ZH0, ZL0, ZH1, ZL1;
            mmDual<2, 64, 7>(tZh, tZl, lnc, kf, wWZh, wWZl, bzv, ZH0, ZL0, ZH1, ZL1);
            stScr(ZH0, ZL0, 0, lng, colz, scrZ, 64);
            stScr(ZH1, ZL1, 1, lng, colz, scrZ, 64);
        }
        FENCE();
        __syncthreads();
        FENCE();

        // ---- PH2: [gate|prop] = h @ GP (2 ct; hi regs, lo global/L2) ----
        {
            f32x4 H[2], L[2], H1[2], L1[2];
#pragma unroll
            for (int j = 0; j < 2; ++j) {
                H[j]  = (f32x4){bGPv[j], bGPv[j], bGPv[j], bGPv[j]};
                H1[j] = H[j];
                L[j]  = (f32x4){0.f, 0.f, 0.f, 0.f};
                L1[j] = L[j];
            }
#pragma unroll
            for (int ks = 0; ks < 4; ++ks) {
                int k = ks * 32 + kf;
                f16x8 a0h = rdA(tHh, lnc, k, 128, 7),      a0l = rdA(tHl, lnc, k, 128, 7);
                f16x8 a1h = rdA(tHh, 16 + lnc, k, 128, 7), a1l = rdA(tHl, 16 + lnc, k, 128, 7);
#pragma unroll
                for (int j = 0; j < 2; ++j) {
                    int colj = ct0 + j * 16;
                    f16x8 bhf = wGPh[j][ks];
                    f16x8 blf = ldB(wa, GPLO, colj, 128, k);
                    H[j]  = MFMA16(a0h, bhf, H[j]);  L[j]  = MFMA16(a0h, blf, L[j]);  L[j]  = MFMA16(a0l, bhf, L[j]);
                    H1[j] = MFMA16(a1h, bhf, H1[j]); L1[j] = MFMA16(a1h, blf, L1[j]); L1[j] = MFMA16(a1l, bhf, L1[j]);
                }
            }
#pragma unroll
            for (int j = 0; j < 2; ++j) {
                stScr(H[j],  L[j],  0, lng, ct0 + j * 16, scrB, 128);
                stScr(H1[j], L1[j], 1, lng, ct0 + j * 16, scrB, 128);
            }
        }
        FENCE();
        __syncthreads();
        FENCE();

        // ---- C1: gate/loc/relu(prop), 8 cols/thread; eps load ----
        {
            epsA = *(const f32x4*)(eps + ((size_t)t * 8192 + r0 + crow) * 64 + cc);
            epsB = *(const f32x4*)(eps + ((size_t)t * 8192 + r0 + crow) * 64 + cc + 4);
#pragma unroll
            for (int h4 = 0; h4 < 2; ++h4) {
                int c4 = cc + h4 * 4;
                f32x4 gp4 = rdS4(scrB, 128, crow, c4);
                f32x4 pr4 = rdS4(scrB, 128, crow, 64 + c4);
                f32x4 zw4 = rdS4(scrZ, 64, crow, c4);
                f32x4 loc4; f16x4 ph4, pl4;
#pragma unroll
                for (int i = 0; i < 4; ++i) {
                    float g = sigm(gp4[i]);
                    loc4[i] = (1.f - g) * zw4[i] + g * pr4[i];
                    float rp = fmaxf(pr4[i], 0.f);
                    _Float16 hi, lo; split2(rp, hi, lo); ph4[i] = hi; pl4[i] = lo;
                }
                wrS4(scrB, 128, crow, 64 + c4, loc4);
                wrF16x4(tPh, 64, crow, c4, ph4);
                wrF16x4(tPl, 64, crow, c4, pl4);
            }
        }
        FENCE();
        __syncthreads();
        FENCE();

        // ---- PH3: spre = relu(prop) @ Wsc (1 ct) -> scrB cols 0-63 ----
        {
            f32x4 SH0, SL0, SH1, SL1;
            mmDual<2, 64, 7>(tPh, tPl, lnc, kf, wSCh, wSCl, bscv, SH0, SL0, SH1, SL1);
            stScr(SH0, SL0, 0, lng, colz, scrB, 128);
            stScr(SH1, SL1, 1, lng, colz, scrB, 128);
        }
        FENCE();
        __syncthreads();
        FENCE();

        // ---- C2: scale, z = loc + scale*eps, base_lp ----
        float lp = 0.f;
#pragma unroll
        for (int h4 = 0; h4 < 2; ++h4) {
            int c4 = cc + h4 * 4;
            f32x4 ev   = (h4 == 0) ? epsA : epsB;
            f32x4 s4   = rdS4(scrB, 128, crow, c4);
            f32x4 loc4 = rdS4(scrB, 128, crow, 64 + c4);
            f16x4 zh4, zl4;
#pragma unroll
            for (int i = 0; i < 4; ++i) {
                float sc = softplusf_(s4[i]) + 0.001f;
                float zv = loc4[i] + sc * ev[i];
                lp += -0.5f * ev[i] * ev[i] - __logf(sc) - HLOG2PI;
                _Float16 hi, lo; split2(zv, hi, lo); zh4[i] = hi; zl4[i] = lo;
            }
            wrF16x4(tZh, 64, crow, c4, zh4);
            wrF16x4(tZl, 64, crow, c4, zl4);
        }
        FENCE();
        __syncthreads();
        FENCE();

        // ---- IAF flows ----
#pragma unroll
        for (int f = 0; f < 2; ++f) {
            {   // hh = relu(z @ W1m + b1) (2 ct)
                f32x4 H[2], L[2], H1[2], L1[2];
#pragma unroll
                for (int j = 0; j < 2; ++j) {
                    H[j]  = (f32x4){bW1v[f][j], bW1v[f][j], bW1v[f][j], bW1v[f][j]};
                    H1[j] = H[j];
                    L[j]  = (f32x4){0.f, 0.f, 0.f, 0.f};
                    L1[j] = L[j];
                }
#pragma unroll
                for (int ks = 0; ks < 2; ++ks) {
                    int k = ks * 32 + kf;
                    f16x8 a0h = rdA(tZh, lnc, k, 64, 7),      a0l = rdA(tZl, lnc, k, 64, 7);
                    f16x8 a1h = rdA(tZh, 16 + lnc, k, 64, 7), a1l = rdA(tZl, 16 + lnc, k, 64, 7);
#pragma unroll
                    for (int j = 0; j < 2; ++j) {
                        H[j]  = MFMA16(a0h, wW1h[f][j][ks], H[j]);  L[j]  = MFMA16(a0h, wW1l[f][j][ks], L[j]);  L[j]  = MFMA16(a0l, wW1h[f][j][ks], L[j]);
                        H1[j] = MFMA16(a1h, wW1h[f][j][ks], H1[j]); L1[j] = MFMA16(a1h, wW1l[f][j][ks], L1[j]); L1[j] = MFMA16(a1l, wW1h[f][j][ks], L1[j]);
                    }
                }
#pragma unroll
                for (int j = 0; j < 2; ++j) {
                    stAct<true>(H[j],  L[j],  0, lng, ct0 + j * 16, tHh, tHl, 128, 7);
                    stAct<true>(H1[j], L1[j], 1, lng, ct0 + j * 16, tHh, tHl, 128, 7);
                }
            }
            FENCE();
            __syncthreads();
            FENCE();
            {   // [mu|spre] = hh @ MS (2 ct; hi regs, lo global/L2)
                f32x4 H[2], L[2], H1[2], L1[2];
#pragma unroll
                for (int j = 0; j < 2; ++j) {
                    H[j]  = (f32x4){bMSv[f][j], bMSv[f][j], bMSv[f][j], bMSv[f][j]};
                    H1[j] = H[j];
                    L[j]  = (f32x4){0.f, 0.f, 0.f, 0.f};
                    L1[j] = L[j];
                }
#pragma unroll
                for (int ks = 0; ks < 4; ++ks) {
                    int k = ks * 32 + kf;
                    f16x8 a0h = rdA(tHh, lnc, k, 128, 7),      a0l = rdA(tHl, lnc, k, 128, 7);
                    f16x8 a1h = rdA(tHh, 16 + lnc, k, 128, 7), a1l = rdA(tHl, 16 + lnc, k, 128, 7);
#pragma unroll
                    for (int j = 0; j < 2; ++j) {
                        int colj = ct0 + j * 16;
                        f16x8 bhf = wMSh[f][j][ks];
                        f16x8 blf = ldB(wa, MSB + f * 32768 + 16384, colj, 128, k);
                        H[j]  = MFMA16(a0h, bhf, H[j]);  L[j]  = MFMA16(a0h, blf, L[j]);  L[j]  = MFMA16(a0l, bhf, L[j]);
                        H1[j] = MFMA16(a1h, bhf, H1[j]); L1[j] = MFMA16(a1h, blf, L1[j]); L1[j] = MFMA16(a1l, bhf, L1[j]);
                    }
                }
#pragma unroll
                for (int j = 0; j < 2; ++j) {
                    stScr(H[j],  L[j],  0, lng, ct0 + j * 16, scrB, 128);
                    stScr(H1[j], L1[j], 1, lng, ct0 + j * 16, scrB, 128);
                }
            }
            FENCE();
            __syncthreads();
            FENCE();
            {   // C3: z = sg*z + (1-sg)*mu; lp -= log(sg)
#pragma unroll
                for (int h4 = 0; h4 < 2; ++h4) {
                    int c4 = cc + h4 * 4;
                    f32x4 mu4 = rdS4(scrB, 128, crow, c4);
                    f32x4 sp4 = rdS4(scrB, 128, crow, 64 + c4);
                    f16x4 zh4 = rdF16x4(tZh, 64, crow, c4);
                    f16x4 zl4 = rdF16x4(tZl, 64, crow, c4);
                    f16x4 nzh, nzl;
#pragma unroll
                    for (int i = 0; i < 4; ++i) {
                        float zv = (float)zh4[i] + (float)zl4[i] * INVLO;
                        float sg = sigm(sp4[i] + 1.0f);
                        float zn = sg * zv + (1.f - sg) * mu4[i];
                        lp -= __logf(sg);
                        _Float16 hi, lo; split2(zn, hi, lo); nzh[i] = hi; nzl[i] = lo;
                    }
                    wrF16x4(tZh, 64, crow, c4, nzh);
                    wrF16x4(tZl, 64, crow, c4, nzl);
                }
                if (f == 1) lpS[crow][tid & 7] = lp;
            }
            FENCE();
            __syncthreads();
            FENCE();
        }

        // ---- PH6: eh = relu(z @ We1 + be1) (2 ct) ----
        {
            f32x4 H[2], L[2], H1[2], L1[2];
#pragma unroll
            for (int j = 0; j < 2; ++j) {
                H[j]  = (f32x4){bE1v[j], bE1v[j], bE1v[j], bE1v[j]};
                H1[j] = H[j];
                L[j]  = (f32x4){0.f, 0.f, 0.f, 0.f};
                L1[j] = L[j];
            }
#pragma unroll
            for (int ks = 0; ks < 2; ++ks) {
                int k = ks * 32 + kf;
                f16x8 a0h = rdA(tZh, lnc, k, 64, 7),      a0l = rdA(tZl, lnc, k, 64, 7);
                f16x8 a1h = rdA(tZh, 16 + lnc, k, 64, 7), a1l = rdA(tZl, 16 + lnc, k, 64, 7);
#pragma unroll
                for (int j = 0; j < 2; ++j) {
                    H[j]  = MFMA16(a0h, wE1h[j][ks], H[j]);  L[j]  = MFMA16(a0h, wE1l[j][ks], L[j]);  L[j]  = MFMA16(a0l, wE1h[j][ks], L[j]);
                    H1[j] = MFMA16(a1h, wE1h[j][ks], H1[j]); L1[j] = MFMA16(a1h, wE1l[j][ks], L1[j]); L1[j] = MFMA16(a1l, wE1h[j][ks], L1[j]);
                }
            }
#pragma unroll
            for (int j = 0; j < 2; ++j) {
                stAct<true>(H[j],  L[j],  0, lng, ct0 + j * 16, tHh, tHl, 128, 7);
                stAct<true>(H1[j], L1[j], 1, lng, ct0 + j * 16, tHh, tHl, 128, 7);
            }
        }
        FENCE();
        __syncthreads();
        FENCE();

        // ---- PH7: e-partials = eh @ We2 (k-half split); stage x(t+1) ----
        {
            f32x4 H0 = {bE2v, bE2v, bE2v, bE2v}, H1 = H0;
            f32x4 L0 = {0.f, 0.f, 0.f, 0.f},     L1 = L0;
#pragma unroll
            for (int ks = 0; ks < 2; ++ks) {
                int k = khE2 * 64 + ks * 32 + kf;
                f16x8 a0h = rdA(tHh, lnc, k, 128, 7),      a0l = rdA(tHl, lnc, k, 128, 7);
                f16x8 a1h = rdA(tHh, 16 + lnc, k, 128, 7), a1l = rdA(tHl, 16 + lnc, k, 128, 7);
                H0 = MFMA16(a0h, wE2h[ks], H0); L0 = MFMA16(a0h, wE2l[ks], L0); L0 = MFMA16(a0l, wE2h[ks], L0);
                H1 = MFMA16(a1h, wE2h[ks], H1); L1 = MFMA16(a1h, wE2l[ks], L1); L1 = MFMA16(a1l, wE2h[ks], L1);
            }
            stScr(H0, L0, 0, lng, khE2 * 64 + colE2, scrB, 128);
            stScr(H1, L1, 1, lng, khE2 * 64 + colE2, scrB, 128);
        }
        if (t + 1 < S) {
            int rr = tid >> 3, d4 = (tid & 7) * 4;
            int ge = ((t + 1) * 64 + b0 + rr) * 32 + d4;
            u64 xh = *(const u64*)(wa + XHI + ge);
            u64 xl = *(const u64*)(wa + XLO + ge);
            int byte = (rr * 64 + d4 * 2) ^ ((rr & 3) << 4);
            *(u64*)((char*)tXh + byte) = xh;
            *(u64*)((char*)tXl + byte) = xl;
        }
        FENCE();
        __syncthreads();
        FENCE();

        // ---- C4: combine e (2 partials), write outputs; zlp ----
        {
#pragma unroll
            for (int q = 0; q < 4; ++q) {
                int col = cg + q;
                float v = rdS1(scrB, 128, erow, col) + rdS1(scrB, 128, erow, 64 + col);
                if (col < 24) {
                    long plane = ((long)(t * 3 + (col >> 3)) * 8 + (col & 7)) * 8192 + r0 + erow;
                    float uvq = u[plane];
                    float sg = sigm(v);
                    bool hit = uvq < sg;
                    out[plane] = hit ? 1.f : 0.f;
                    out[XLP_OFF + plane] = hit ? logsigm(v) : logsigm(-v);
                } else {
                    long pf = ((long)t * 8 + (col & 7)) * 8192 + r0 + erow;
                    out[FRAC_OFF + pf] = sigm(v);
                }
            }
            if (tid < 32) {
                float s = 0.f;
#pragma unroll
                for (int g2 = 0; g2 < 8; ++g2) s += lpS[tid][g2];
                out[ZLP_OFF + (long)t * 8192 + r0 + tid] = s;
            }
        }
        FENCE();
        // no trailing barrier: next PH1 writes tH/scrZ only; C4 reads scrB/lpS;
        // PH2's scrB write is behind PH1's end-of-phase barrier.
    }
}

extern "C" void kernel_launch(void* const* d_in, const int* in_sizes, int n_in,
                              void* d_out, int out_size, void* d_ws, size_t ws_size,
                              hipStream_t stream)
{
    const float* input = (const float*)d_in[0];
    const float* eps   = (const float*)d_in[1];
    const float* u     = (const float*)d_in[2];
    const float* Wxh   = (const float*)d_in[3];
    const float* Wzh   = (const float*)d_in[4];
    const float* bh    = (const float*)d_in[5];
    const float* Wg    = (const float*)d_in[6];
    const float* bg    = (const float*)d_in[7];
    const float* Wp    = (const float*)d_in[8];
    const float* bp    = (const float*)d_in[9];
    const float* Wz    = (const float*)d_in[10];
    const float* bz    = (const float*)d_in[11];
    const float* Wsc   = (const float*)d_in[12];
    const float* bsc   = (const float*)d_in[13];
    const float* W1    = (const float*)d_in[14];
    const float* b1    = (const float*)d_in[15];
    const float* Wm    = (const float*)d_in[16];
    const float* bm    = (const float*)d_in[17];
    const float* Ws    = (const float*)d_in[18];
    const float* bs    = (const float*)d_in[19];
    const float* We1   = (const float*)d_in[20];
    const float* be1   = (const float*)d_in[21];
    const float* We2   = (const float*)d_in[22];
    const float* be2   = (const float*)d_in[23];

    u16* wa = (u16*)d_ws;   // ~1.45 MB used

    hipLaunchKernelGGL(prep_kernel, dim3(1408), dim3(256), 0, stream,
                       input, Wxh, Wzh, Wg, Wp, Wz, Wsc, W1, Wm, Ws, We1, We2, wa);

    hipLaunchKernelGGL(ssm_mfma_kernel, dim3(256), dim3(256), 0, stream,
                       eps, u, bh, bg, bp, bz, bsc, b1, bm, bs, be1, be2,
                       wa, (float*)d_out);
}

// Round 16
// 2641.948 us; speedup vs baseline: 1.9966x; 1.9966x over previous
//
#include <hip/hip_runtime.h>

// ---------------------------------------------------------------------------
// SSM evaluator, MFMA version, R16 = R12 restored (best known, 2642us) with
// post-barrier sched fences removed (pre-barrier fences kept). R13-R15 all
// regressed (AGPR parking -> per-use accvgpr_read chains; seq-rt -> lost ILP;
// 2 blocks/CU impossible at grid=256=CU count; lo-from-global -> L2 thrash).
// Post-fences only blocked benign addr-calc overlap into barrier shadows:
// LDS reads can't hoist above s_barrier regardless.
// ---------------------------------------------------------------------------

typedef _Float16 f16x8 __attribute__((ext_vector_type(8)));
typedef _Float16 f16x4 __attribute__((ext_vector_type(4)));
typedef float    f32x4 __attribute__((ext_vector_type(4)));
typedef unsigned short u16;
typedef unsigned long long u64;

#define MFMA16(a,b,c) __builtin_amdgcn_mfma_f32_16x16x32_f16((a),(b),(c),0,0,0)
#define FENCE() __builtin_amdgcn_sched_barrier(0)

namespace {
constexpr int S = 128;
constexpr long FRAC_OFF = 25165824L;
constexpr long XLP_OFF  = 33554432L;
constexpr long ZLP_OFF  = 58720256L;
constexpr float HLOG2PI = 0.91893853320467274f;
constexpr float INVLO   = 1.0f / 2048.0f;

// ws arena offsets (u16 elements). [col][k] layout, hi then lo.
constexpr int C1HI = 0,      C1LO = 12288;   // [128][96]
constexpr int GPHI = 24576,  GPLO = 40960;   // [128][128]
constexpr int WZHI = 57344,  WZLO = 61440;   // [64][64]
constexpr int SCHI = 65536,  SCLO = 69632;   // [64][64]
constexpr int W1B  = 73728;                  // +f*16384 hi, +8192 lo [128][64]
constexpr int MSB  = 106496;                 // +f*32768 hi, +16384 lo [128][128]
constexpr int E1HI = 172032, E1LO = 180224;  // [128][64]
constexpr int E2HI = 188416, E2LO = 192512;  // [32][128]
constexpr int XHI  = 196608, XLO  = 458752;  // input split planes
}

__device__ __forceinline__ float sigm(float x)      { return 1.0f / (1.0f + __expf(-x)); }
__device__ __forceinline__ float softplusf_(float x){ return fmaxf(x, 0.f) + __logf(1.f + __expf(-fabsf(x))); }
__device__ __forceinline__ float logsigm(float x)   { return fminf(x, 0.f) - __logf(1.f + __expf(-fabsf(x))); }

__device__ __forceinline__ void split2(float v, _Float16& hi, _Float16& lo) {
    hi = (_Float16)v;
    lo = (_Float16)((v - (float)hi) * 2048.0f);
}

__device__ __forceinline__ f16x8 rdA(const u16* t, int row, int k, int strideEls, int swm) {
    int byte = ((row * strideEls + k) * 2) ^ ((row & swm) << 4);
    return *(const f16x8*)((const char*)t + byte);
}
__device__ __forceinline__ f16x8 ldB(const u16* wa, int base, int col, int K, int koff) {
    return *(const f16x8*)(wa + base + col * K + koff);
}
__device__ __forceinline__ f16x8 ldLo(const u16* lds, int el, int col) {
    int byte = (el * 2) ^ ((col & 7) << 4);
    return *(const f16x8*)((const char*)lds + byte);
}

// single-col-tile dual-row-tile job, both planes in regs (Wz/Wsc etc.)
template<int NKS, int STRIDE, int SWM>
__device__ __forceinline__ void mmDual(const u16* Th, const u16* Tl, int lnc, int kf,
                                       const f16x8 (&wh)[NKS], const f16x8 (&wl)[NKS],
                                       float bias, f32x4& H0, f32x4& L0, f32x4& H1, f32x4& L1)
{
    H0 = (f32x4){bias, bias, bias, bias}; H1 = H0;
    L0 = (f32x4){0.f, 0.f, 0.f, 0.f};     L1 = L0;
#pragma unroll
    for (int ks = 0; ks < NKS; ++ks) {
        int k = ks * 32 + kf;
        f16x8 a0h = rdA(Th, lnc,      k, STRIDE, SWM);
        f16x8 a0l = rdA(Tl, lnc,      k, STRIDE, SWM);
        f16x8 a1h = rdA(Th, 16 + lnc, k, STRIDE, SWM);
        f16x8 a1l = rdA(Tl, 16 + lnc, k, STRIDE, SWM);
        H0 = MFMA16(a0h, wh[ks], H0); L0 = MFMA16(a0h, wl[ks], L0); L0 = MFMA16(a0l, wh[ks], L0);
        H1 = MFMA16(a1h, wh[ks], H1); L1 = MFMA16(a1h, wl[ks], L1); L1 = MFMA16(a1l, wh[ks], L1);
    }
}

template<bool RELU>
__device__ __forceinline__ void stAct(f32x4 H, f32x4 L, int rt, int lng, int col,
                                      u16* th, u16* tl, int strideEls, int swm)
{
#pragma unroll
    for (int q = 0; q < 4; ++q) {
        int row = rt * 16 + lng * 4 + q;
        float v = H[q] + L[q] * INVLO;
        if (RELU) v = fmaxf(v, 0.f);
        _Float16 hi, lo; split2(v, hi, lo);
        int byte = ((row * strideEls + col) * 2) ^ ((row & swm) << 4);
        *(_Float16*)((char*)th + byte) = hi;
        *(_Float16*)((char*)tl + byte) = lo;
    }
}
__device__ __forceinline__ void stScr(f32x4 H, f32x4 L, int rt, int lng, int col,
                                      float* s, int strideEls)
{
#pragma unroll
    for (int q = 0; q < 4; ++q) {
        int row = rt * 16 + lng * 4 + q;
        int byte = ((row * strideEls + col) * 4) ^ ((row & 7) << 4);
        *(float*)((char*)s + byte) = H[q] + L[q] * INVLO;
    }
}
__device__ __forceinline__ f32x4 rdS4(const float* s, int strideEls, int row, int c) {
    int byte = ((row * strideEls + c) * 4) ^ ((row & 7) << 4);
    return *(const f32x4*)((const char*)s + byte);
}
__device__ __forceinline__ float rdS1(const float* s, int strideEls, int row, int c) {
    int byte = ((row * strideEls + c) * 4) ^ ((row & 7) << 4);
    return *(const float*)((const char*)s + byte);
}
__device__ __forceinline__ void wrS4(float* s, int strideEls, int row, int c, f32x4 v) {
    int byte = ((row * strideEls + c) * 4) ^ ((row & 7) << 4);
    *(f32x4*)((char*)s + byte) = v;
}
__device__ __forceinline__ void wrF16x4(u16* t, int strideEls, int row, int c, f16x4 v) {
    int byte = ((row * strideEls + c) * 2) ^ ((row & 7) << 4);
    *(f16x4*)((char*)t + byte) = v;
}
__device__ __forceinline__ f16x4 rdF16x4(const u16* t, int strideEls, int row, int c) {
    int byte = ((row * strideEls + c) * 2) ^ ((row & 7) << 4);
    return *(const f16x4*)((const char*)t + byte);
}

// --- prep: build masked/stacked/transposed/split weights + split input ------
__global__ void prep_kernel(const float* __restrict__ input,
                            const float* __restrict__ Wxh, const float* __restrict__ Wzh,
                            const float* __restrict__ Wg,  const float* __restrict__ Wp,
                            const float* __restrict__ Wz,  const float* __restrict__ Wsc,
                            const float* __restrict__ W1,  const float* __restrict__ Wm,
                            const float* __restrict__ Ws_, const float* __restrict__ We1,
                            const float* __restrict__ We2, u16* __restrict__ wa)
{
    int idx = blockIdx.x * 256 + threadIdx.x;
    if (idx < 98304) {
        int hio = 0, loo = 0; float v = 0.f;
        int i = idx;
        if (i < 12288) {
            int col = i / 96, k = i % 96;
            v = (k < 32) ? Wxh[k * 128 + col] : Wzh[(k - 32) * 128 + col];
            hio = C1HI + i; loo = C1LO + i;
        } else if (i < 28672) { int j = i - 12288;
            int col = j >> 7, k = j & 127;
            v = (col < 64) ? Wg[k * 64 + col] : Wp[k * 64 + col - 64];
            hio = GPHI + j; loo = GPLO + j;
        } else if (i < 32768) { int j = i - 28672;
            int col = j >> 6, k = j & 63; v = Wz[k * 64 + col];
            hio = WZHI + j; loo = WZLO + j;
        } else if (i < 36864) { int j = i - 32768;
            int col = j >> 6, k = j & 63; v = Wsc[k * 64 + col];
            hio = SCHI + j; loo = SCLO + j;
        } else if (i < 53248) { int j = i - 36864;
            int f = j >> 13, jj = j & 8191;
            int col = jj >> 6, k = jj & 63;
            v = W1[(f * 64 + k) * 128 + col] * (((col % 63) >= k) ? 1.f : 0.f);
            hio = W1B + f * 16384 + jj; loo = hio + 8192;
        } else if (i < 86016) { int j = i - 53248;
            int f = j >> 14, jj = j & 16383;
            int col = jj >> 7, k = jj & 127;
            if (col < 64) v = Wm[(f * 128 + k) * 64 + col] * (((k % 63) < col) ? 1.f : 0.f);
            else { int c = col - 64;
                   v = Ws_[(f * 128 + k) * 64 + c]         * (((k % 63) < c)   ? 1.f : 0.f); }
            hio = MSB + f * 32768 + jj; loo = hio + 16384;
        } else if (i < 94208) { int j = i - 86016;
            int col = j >> 6, k = j & 63; v = We1[k * 128 + col];
            hio = E1HI + j; loo = E1LO + j;
        } else { int j = i - 94208;
            int col = j >> 7, k = j & 127; v = We2[k * 32 + col];
            hio = E2HI + j; loo = E2LO + j;
        }
        _Float16 hi, lo; split2(v, hi, lo);
        wa[hio] = __builtin_bit_cast(u16, hi);
        wa[loo] = __builtin_bit_cast(u16, lo);
    } else {
        int j = idx - 98304;
        if (j < 262144) {
            float v = input[j];
            _Float16 hi, lo; split2(v, hi, lo);
            wa[XHI + j] = __builtin_bit_cast(u16, hi);
            wa[XLO + j] = __builtin_bit_cast(u16, lo);
        }
    }
}

// --- main scan kernel -------------------------------------------------------
__global__ __launch_bounds__(256, 1)
void ssm_mfma_kernel(const float* __restrict__ eps, const float* __restrict__ u,
                     const float* __restrict__ bh,  const float* __restrict__ bg,
                     const float* __restrict__ bp,  const float* __restrict__ bz,
                     const float* __restrict__ bsc, const float* __restrict__ b1,
                     const float* __restrict__ bm,  const float* __restrict__ bs,
                     const float* __restrict__ be1, const float* __restrict__ be2,
                     const u16* __restrict__ wa, float* __restrict__ out)
{
    __shared__ u16 tXh[32 * 32],  tXl[32 * 32];
    __shared__ u16 tZh[32 * 64],  tZl[32 * 64];
    __shared__ u16 tHh[32 * 128], tHl[32 * 128];
    __shared__ u16 tPh[32 * 64],  tPl[32 * 64];
    __shared__ float scrB[32 * 128];               // scratch; cols 64-127 double as loc
    __shared__ float scrZ[32 * 64];
    __shared__ float lpS[32][9];
    __shared__ u16 loMS[32768];                    // MS lo-planes, swizzled
    __shared__ u16 loGP[16384];                    // GP lo-plane,  swizzled

    const int tid = threadIdx.x;
    const int ln  = tid & 63, w = tid >> 6;        // wave 0..3
    const int lnc = ln & 15, lng = ln >> 4;
    const int r0  = blockIdx.x * 32, b0 = r0 & 63;
    const int kf  = lng * 8;
    const int ct0   = w * 32 + lnc;                // first col-tile (128-col mats)
    const int colz  = w * 16 + lnc;                // Wz AND Wsc tile
    const int colE2 = (w & 1) * 16 + lnc;          // E2 col
    const int khE2  = w >> 1;                      // E2 k-half (64 k each)
    const int crow  = tid >> 3, cc = (tid & 7) * 8;       // C-phase: 8 cols/thread
    const int erow  = tid & 31, cg = (tid >> 5) * 4;      // C4: 4 cols/thread

    // ---- one-time: stage lo-planes of MS/GP into swizzled LDS ----
    for (int i8 = tid; i8 < 4096; i8 += 256) {
        int el = i8 * 8;
        int f = el >> 14, rem = el & 16383, col = rem >> 7;
        f16x8 v = *(const f16x8*)(wa + MSB + f * 32768 + 16384 + rem);
        int byte = (el * 2) ^ ((col & 7) << 4);
        *(f16x8*)((char*)loMS + byte) = v;
    }
    for (int i8 = tid; i8 < 2048; i8 += 256) {
        int el = i8 * 8;
        int col = el >> 7;
        f16x8 v = *(const f16x8*)(wa + GPLO + el);
        int byte = (el * 2) ^ ((col & 7) << 4);
        *(f16x8*)((char*)loGP + byte) = v;
    }

    // ---- one-time: this wave's weight tiles -> registers (all static idx) ----
    f16x8 wC1h[2][3], wC1l[2][3];        // [ct][ks]
    f16x8 wGPh[2][4];                    // hi only (lo in LDS)
    f16x8 wWZh[2], wWZl[2], wSCh[2], wSCl[2];
    f16x8 wW1h[2][2][2], wW1l[2][2][2];  // [f][ct][ks]
    f16x8 wMSh[2][2][4];                 // [f][ct][ks], hi only
    f16x8 wE1h[2][2], wE1l[2][2];        // [ct][ks]
    f16x8 wE2h[2], wE2l[2];              // [ks] within k-half
#pragma unroll
    for (int j = 0; j < 2; ++j) {
        int colj = ct0 + j * 16;
#pragma unroll
        for (int ks = 0; ks < 3; ++ks) {
            wC1h[j][ks] = ldB(wa, C1HI, colj, 96, ks * 32 + kf);
            wC1l[j][ks] = ldB(wa, C1LO, colj, 96, ks * 32 + kf);
        }
#pragma unroll
        for (int ks = 0; ks < 4; ++ks)
            wGPh[j][ks] = ldB(wa, GPHI, colj, 128, ks * 32 + kf);
#pragma unroll
        for (int ks = 0; ks < 2; ++ks) {
            wE1h[j][ks] = ldB(wa, E1HI, colj, 64, ks * 32 + kf);
            wE1l[j][ks] = ldB(wa, E1LO, colj, 64, ks * 32 + kf);
        }
#pragma unroll
        for (int f = 0; f < 2; ++f) {
#pragma unroll
            for (int ks = 0; ks < 2; ++ks) {
                wW1h[f][j][ks] = ldB(wa, W1B + f * 16384,        colj, 64, ks * 32 + kf);
                wW1l[f][j][ks] = ldB(wa, W1B + f * 16384 + 8192, colj, 64, ks * 32 + kf);
            }
#pragma unroll
            for (int ks = 0; ks < 4; ++ks)
                wMSh[f][j][ks] = ldB(wa, MSB + f * 32768, colj, 128, ks * 32 + kf);
        }
    }
#pragma unroll
    for (int ks = 0; ks < 2; ++ks) {
        wWZh[ks] = ldB(wa, WZHI, colz, 64, ks * 32 + kf);
        wWZl[ks] = ldB(wa, WZLO, colz, 64, ks * 32 + kf);
        wSCh[ks] = ldB(wa, SCHI, colz, 64, ks * 32 + kf);
        wSCl[ks] = ldB(wa, SCLO, colz, 64, ks * 32 + kf);
        wE2h[ks] = ldB(wa, E2HI, colE2, 128, khE2 * 64 + ks * 32 + kf);
        wE2l[ks] = ldB(wa, E2LO, colE2, 128, khE2 * 64 + ks * 32 + kf);
    }

    // biases
    float bhv[2], bGPv[2], bW1v[2][2], bMSv[2][2], bE1v[2];
#pragma unroll
    for (int j = 0; j < 2; ++j) {
        int colj = ct0 + j * 16;
        bhv[j]  = bh[colj];
        bGPv[j] = (colj < 64) ? bg[colj] : bp[colj - 64];
        bE1v[j] = be1[colj];
#pragma unroll
        for (int f = 0; f < 2; ++f) {
            bW1v[f][j] = b1[f * 128 + colj];
            bMSv[f][j] = (colj < 64) ? bm[f * 64 + colj] : bs[f * 64 + colj - 64];
        }
    }
    const float bzv  = bz[colz];
    const float bscv = bsc[colz];
    const float bE2v = (khE2 == 0) ? be2[colE2] : 0.f;

    // init z=0, stage x(t=0)
    for (int i = tid; i < 32 * 64; i += 256) { tZh[i] = 0; tZl[i] = 0; }
    {
        int rr = tid >> 3, d4 = (tid & 7) * 4;
        int ge = (b0 + rr) * 32 + d4;
        u64 xh = *(const u64*)(wa + XHI + ge);
        u64 xl = *(const u64*)(wa + XLO + ge);
        int byte = (rr * 64 + d4 * 2) ^ ((rr & 3) << 4);
        *(u64*)((char*)tXh + byte) = xh;
        *(u64*)((char*)tXl + byte) = xl;
    }
    FENCE();
    __syncthreads();

    for (int t = 0; t < S; ++t) {
        f32x4 epsA, epsB;   // loaded in C1, consumed in C2

        // ---- PH1: h = relu([x,z]@C1 + bh) (2 ct) ; zwz = z@Wz (1 ct) ----
        {
            f32x4 H[2], L[2], H1[2], L1[2];
#pragma unroll
            for (int j = 0; j < 2; ++j) {
                H[j]  = (f32x4){bhv[j], bhv[j], bhv[j], bhv[j]};
                H1[j] = H[j];
                L[j]  = (f32x4){0.f, 0.f, 0.f, 0.f};
                L1[j] = L[j];
            }
#pragma unroll
            for (int ks = 0; ks < 3; ++ks) {
                f16x8 a0h, a0l, a1h, a1l;
                if (ks == 0) {
                    a0h = rdA(tXh, lnc, kf, 32, 3);      a0l = rdA(tXl, lnc, kf, 32, 3);
                    a1h = rdA(tXh, 16 + lnc, kf, 32, 3); a1l = rdA(tXl, 16 + lnc, kf, 32, 3);
                } else {
                    int k = (ks - 1) * 32 + kf;
                    a0h = rdA(tZh, lnc, k, 64, 7);       a0l = rdA(tZl, lnc, k, 64, 7);
                    a1h = rdA(tZh, 16 + lnc, k, 64, 7);  a1l = rdA(tZl, 16 + lnc, k, 64, 7);
                }
#pragma unroll
                for (int j = 0; j < 2; ++j) {
                    H[j]  = MFMA16(a0h, wC1h[j][ks], H[j]);  L[j]  = MFMA16(a0h, wC1l[j][ks], L[j]);  L[j]  = MFMA16(a0l, wC1h[j][ks], L[j]);
                    H1[j] = MFMA16(a1h, wC1h[j][ks], H1[j]); L1[j] = MFMA16(a1h, wC1l[j][ks], L1[j]); L1[j] = MFMA16(a1l, wC1h[j][ks], L1[j]);
                }
            }
#pragma unroll
            for (int j = 0; j < 2; ++j) {
                stAct<true>(H[j],  L[j],  0, lng, ct0 + j * 16, tHh, tHl, 128, 7);
                stAct<true>(H1[j], L1[j], 1, lng, ct0 + j * 16, tHh, tHl, 128, 7);
            }
        }
        {
            f32x4 ZH0, ZL0, ZH1, ZL1;
            mmDual<2, 64, 7>(tZh, tZl, lnc, kf, wWZh, wWZl, bzv, ZH0, ZL0, ZH1, ZL1);
            stScr(ZH0, ZL0, 0, lng, colz, scrZ, 64);
            stScr(ZH1, ZL1, 1, lng, colz, scrZ, 64);
        }
        FENCE();
        __syncthreads();

        // ---- PH2: [gate|prop] = h @ GP (2 ct; hi regs, lo LDS) ----
        {
            f32x4 H[2], L[2], H1[2], L1[2];
#pragma unroll
            for (int j = 0; j < 2; ++j) {
                H[j]  = (f32x4){bGPv[j], bGPv[j], bGPv[j], bGPv[j]};
                H1[j] = H[j];
                L[j]  = (f32x4){0.f, 0.f, 0.f, 0.f};
                L1[j] = L[j];
            }
#pragma unroll
            for (int ks = 0; ks < 4; ++ks) {
                int k = ks * 32 + kf;
                f16x8 a0h = rdA(tHh, lnc, k, 128, 7),      a0l = rdA(tHl, lnc, k, 128, 7);
                f16x8 a1h = rdA(tHh, 16 + lnc, k, 128, 7), a1l = rdA(tHl, 16 + lnc, k, 128, 7);
#pragma unroll
                for (int j = 0; j < 2; ++j) {
                    int colj = ct0 + j * 16;
                    f16x8 bhf = wGPh[j][ks];
                    f16x8 blf = ldLo(loGP, colj * 128 + k, colj);
                    H[j]  = MFMA16(a0h, bhf, H[j]);  L[j]  = MFMA16(a0h, blf, L[j]);  L[j]  = MFMA16(a0l, bhf, L[j]);
                    H1[j] = MFMA16(a1h, bhf, H1[j]); L1[j] = MFMA16(a1h, blf, L1[j]); L1[j] = MFMA16(a1l, bhf, L1[j]);
                }
            }
#pragma unroll
            for (int j = 0; j < 2; ++j) {
                stScr(H[j],  L[j],  0, lng, ct0 + j * 16, scrB, 128);
                stScr(H1[j], L1[j], 1, lng, ct0 + j * 16, scrB, 128);
            }
        }
        FENCE();
        __syncthreads();

        // ---- C1: gate/loc/relu(prop), 8 cols/thread; eps load ----
        {
            epsA = *(const f32x4*)(eps + ((size_t)t * 8192 + r0 + crow) * 64 + cc);
            epsB = *(const f32x4*)(eps + ((size_t)t * 8192 + r0 + crow) * 64 + cc + 4);
#pragma unroll
            for (int h4 = 0; h4 < 2; ++h4) {
                int c4 = cc + h4 * 4;
                f32x4 gp4 = rdS4(scrB, 128, crow, c4);
                f32x4 pr4 = rdS4(scrB, 128, crow, 64 + c4);
                f32x4 zw4 = rdS4(scrZ, 64, crow, c4);
                f32x4 loc4; f16x4 ph4, pl4;
#pragma unroll
                for (int i = 0; i < 4; ++i) {
                    float g = sigm(gp4[i]);
                    loc4[i] = (1.f - g) * zw4[i] + g * pr4[i];
                    float rp = fmaxf(pr4[i], 0.f);
                    _Float16 hi, lo; split2(rp, hi, lo); ph4[i] = hi; pl4[i] = lo;
                }
                wrS4(scrB, 128, crow, 64 + c4, loc4);
                wrF16x4(tPh, 64, crow, c4, ph4);
                wrF16x4(tPl, 64, crow, c4, pl4);
            }
        }
        FENCE();
        __syncthreads();

        // ---- PH3: spre = relu(prop) @ Wsc (1 ct) -> scrB cols 0-63 ----
        {
            f32x4 SH0, SL0, SH1, SL1;
            mmDual<2, 64, 7>(tPh, tPl, lnc, kf, wSCh, wSCl, bscv, SH0, SL0, SH1, SL1);
            stScr(SH0, SL0, 0, lng, colz, scrB, 128);
            stScr(SH1, SL1, 1, lng, colz, scrB, 128);
        }
        FENCE();
        __syncthreads();

        // ---- C2: scale, z = loc + scale*eps, base_lp ----
        float lp = 0.f;
#pragma unroll
        for (int h4 = 0; h4 < 2; ++h4) {
            int c4 = cc + h4 * 4;
            f32x4 ev   = (h4 == 0) ? epsA : epsB;
            f32x4 s4   = rdS4(scrB, 128, crow, c4);
            f32x4 loc4 = rdS4(scrB, 128, crow, 64 + c4);
            f16x4 zh4, zl4;
#pragma unroll
            for (int i = 0; i < 4; ++i) {
                float sc = softplusf_(s4[i]) + 0.001f;
                float zv = loc4[i] + sc * ev[i];
                lp += -0.5f * ev[i] * ev[i] - __logf(sc) - HLOG2PI;
                _Float16 hi, lo; split2(zv, hi, lo); zh4[i] = hi; zl4[i] = lo;
            }
            wrF16x4(tZh, 64, crow, c4, zh4);
            wrF16x4(tZl, 64, crow, c4, zl4);
        }
        FENCE();
        __syncthreads();

        // ---- IAF flows ----
#pragma unroll
        for (int f = 0; f < 2; ++f) {
            {   // hh = relu(z @ W1m + b1) (2 ct)
                f32x4 H[2], L[2], H1[2], L1[2];
#pragma unroll
                for (int j = 0; j < 2; ++j) {
                    H[j]  = (f32x4){bW1v[f][j], bW1v[f][j], bW1v[f][j], bW1v[f][j]};
                    H1[j] = H[j];
                    L[j]  = (f32x4){0.f, 0.f, 0.f, 0.f};
                    L1[j] = L[j];
                }
#pragma unroll
                for (int ks = 0; ks < 2; ++ks) {
                    int k = ks * 32 + kf;
                    f16x8 a0h = rdA(tZh, lnc, k, 64, 7),      a0l = rdA(tZl, lnc, k, 64, 7);
                    f16x8 a1h = rdA(tZh, 16 + lnc, k, 64, 7), a1l = rdA(tZl, 16 + lnc, k, 64, 7);
#pragma unroll
                    for (int j = 0; j < 2; ++j) {
                        H[j]  = MFMA16(a0h, wW1h[f][j][ks], H[j]);  L[j]  = MFMA16(a0h, wW1l[f][j][ks], L[j]);  L[j]  = MFMA16(a0l, wW1h[f][j][ks], L[j]);
                        H1[j] = MFMA16(a1h, wW1h[f][j][ks], H1[j]); L1[j] = MFMA16(a1h, wW1l[f][j][ks], L1[j]); L1[j] = MFMA16(a1l, wW1h[f][j][ks], L1[j]);
                    }
                }
#pragma unroll
                for (int j = 0; j < 2; ++j) {
                    stAct<true>(H[j],  L[j],  0, lng, ct0 + j * 16, tHh, tHl, 128, 7);
                    stAct<true>(H1[j], L1[j], 1, lng, ct0 + j * 16, tHh, tHl, 128, 7);
                }
            }
            FENCE();
            __syncthreads();
            {   // [mu|spre] = hh @ MS (2 ct; hi regs, lo LDS)
                f32x4 H[2], L[2], H1[2], L1[2];
#pragma unroll
                for (int j = 0; j < 2; ++j) {
                    H[j]  = (f32x4){bMSv[f][j], bMSv[f][j], bMSv[f][j], bMSv[f][j]};
                    H1[j] = H[j];
                    L[j]  = (f32x4){0.f, 0.f, 0.f, 0.f};
                    L1[j] = L[j];
                }
#pragma unroll
                for (int ks = 0; ks < 4; ++ks) {
                    int k = ks * 32 + kf;
                    f16x8 a0h = rdA(tHh, lnc, k, 128, 7),      a0l = rdA(tHl, lnc, k, 128, 7);
                    f16x8 a1h = rdA(tHh, 16 + lnc, k, 128, 7), a1l = rdA(tHl, 16 + lnc, k, 128, 7);
#pragma unroll
                    for (int j = 0; j < 2; ++j) {
                        int colj = ct0 + j * 16;
                        f16x8 bhf = wMSh[f][j][ks];
                        f16x8 blf = ldLo(loMS, f * 16384 + colj * 128 + k, colj);
                        H[j]  = MFMA16(a0h, bhf, H[j]);  L[j]  = MFMA16(a0h, blf, L[j]);  L[j]  = MFMA16(a0l, bhf, L[j]);
                        H1[j] = MFMA16(a1h, bhf, H1[j]); L1[j] = MFMA16(a1h, blf, L1[j]); L1[j] = MFMA16(a1l, bhf, L1[j]);
                    }
                }
#pragma unroll
                for (int j = 0; j < 2; ++j) {
                    stScr(H[j],  L[j],  0, lng, ct0 + j * 16, scrB, 128);
                    stScr(H1[j], L1[j], 1, lng, ct0 + j * 16, scrB, 128);
                }
            }
            FENCE();
            __syncthreads();
            {   // C3: z = sg*z + (1-sg)*mu; lp -= log(sg)
#pragma unroll
                for (int h4 = 0; h4 < 2; ++h4) {
                    int c4 = cc + h4 * 4;
                    f32x4 mu4 = rdS4(scrB, 128, crow, c4);
                    f32x4 sp4 = rdS4(scrB, 128, crow, 64 + c4);
                    f16x4 zh4 = rdF16x4(tZh, 64, crow, c4);
                    f16x4 zl4 = rdF16x4(tZl, 64, crow, c4);
                    f16x4 nzh, nzl;
#pragma unroll
                    for (int i = 0; i < 4; ++i) {
                        float zv = (float)zh4[i] + (float)zl4[i] * INVLO;
                        float sg = sigm(sp4[i] + 1.0f);
                        float zn = sg * zv + (1.f - sg) * mu4[i];
                        lp -= __logf(sg);
                        _Float16 hi, lo; split2(zn, hi, lo); nzh[i] = hi; nzl[i] = lo;
                    }
                    wrF16x4(tZh, 64, crow, c4, nzh);
                    wrF16x4(tZl, 64, crow, c4, nzl);
                }
                if (f == 1) lpS[crow][tid & 7] = lp;
            }
            FENCE();
            __syncthreads();
        }

        // ---- PH6: eh = relu(z @ We1 + be1) (2 ct) ----
        {
            f32x4 H[2], L[2], H1[2], L1[2];
#pragma unroll
            for (int j = 0; j < 2; ++j) {
                H[j]  = (f32x4){bE1v[j], bE1v[j], bE1v[j], bE1v[j]};
                H1[j] = H[j];
                L[j]  = (f32x4){0.f, 0.f, 0.f, 0.f};
                L1[j] = L[j];
            }
#pragma unroll
            for (int ks = 0; ks < 2; ++ks) {
                int k = ks * 32 + kf;
                f16x8 a0h = rdA(tZh, lnc, k, 64, 7),      a0l = rdA(tZl, lnc, k, 64, 7);
                f16x8 a1h = rdA(tZh, 16 + lnc, k, 64, 7), a1l = rdA(tZl, 16 + lnc, k, 64, 7);
#pragma unroll
                for (int j = 0; j < 2; ++j) {
                    H[j]  = MFMA16(a0h, wE1h[j][ks], H[j]);  L[j]  = MFMA16(a0h, wE1l[j][ks], L[j]);  L[j]  = MFMA16(a0l, wE1h[j][ks], L[j]);
                    H1[j] = MFMA16(a1h, wE1h[j][ks], H1[j]); L1[j] = MFMA16(a1h, wE1l[j][ks], L1[j]); L1[j] = MFMA16(a1l, wE1h[j][ks], L1[j]);
                }
            }
#pragma unroll
            for (int j = 0; j < 2; ++j) {
                stAct<true>(H[j],  L[j],  0, lng, ct0 + j * 16, tHh, tHl, 128, 7);
                stAct<true>(H1[j], L1[j], 1, lng, ct0 + j * 16, tHh, tHl, 128, 7);
            }
        }
        FENCE();
        __syncthreads();

        // ---- PH7: e-partials = eh @ We2 (k-half split); stage x(t+1) ----
        {
            f32x4 H0 = {bE2v, bE2v, bE2v, bE2v}, H1 = H0;
            f32x4 L0 = {0.f, 0.f, 0.f, 0.f},     L1 = L0;
#pragma unroll
            for (int ks = 0; ks < 2; ++ks) {
                int k = khE2 * 64 + ks * 32 + kf;
                f16x8 a0h = rdA(tHh, lnc, k, 128, 7),      a0l = rdA(tHl, lnc, k, 128, 7);
                f16x8 a1h = rdA(tHh, 16 + lnc, k, 128, 7), a1l = rdA(tHl, 16 + lnc, k, 128, 7);
                H0 = MFMA16(a0h, wE2h[ks], H0); L0 = MFMA16(a0h, wE2l[ks], L0); L0 = MFMA16(a0l, wE2h[ks], L0);
                H1 = MFMA16(a1h, wE2h[ks], H1); L1 = MFMA16(a1h, wE2l[ks], L1); L1 = MFMA16(a1l, wE2h[ks], L1);
            }
            stScr(H0, L0, 0, lng, khE2 * 64 + colE2, scrB, 128);
            stScr(H1, L1, 1, lng, khE2 * 64 + colE2, scrB, 128);
        }
        if (t + 1 < S) {
            int rr = tid >> 3, d4 = (tid & 7) * 4;
            int ge = ((t + 1) * 64 + b0 + rr) * 32 + d4;
            u64 xh = *(const u64*)(wa + XHI + ge);
            u64 xl = *(const u64*)(wa + XLO + ge);
            int byte = (rr * 64 + d4 * 2) ^ ((rr & 3) << 4);
            *(u64*)((char*)tXh + byte) = xh;
            *(u64*)((char*)tXl + byte) = xl;
        }
        FENCE();
        __syncthreads();

        // ---- C4: combine e (2 partials), write outputs; zlp ----
        {
#pragma unroll
            for (int q = 0; q < 4; ++q) {
                int col = cg + q;
                float v = rdS1(scrB, 128, erow, col) + rdS1(scrB, 128, erow, 64 + col);
                if (col < 24) {
                    long plane = ((long)(t * 3 + (col >> 3)) * 8 + (col & 7)) * 8192 + r0 + erow;
                    float uvq = u[plane];
                    float sg = sigm(v);
                    bool hit = uvq < sg;
                    out[plane] = hit ? 1.f : 0.f;
                    out[XLP_OFF + plane] = hit ? logsigm(v) : logsigm(-v);
                } else {
                    long pf = ((long)t * 8 + (col & 7)) * 8192 + r0 + erow;
                    out[FRAC_OFF + pf] = sigm(v);
                }
            }
            if (tid < 32) {
                float s = 0.f;
#pragma unroll
                for (int g2 = 0; g2 < 8; ++g2) s += lpS[tid][g2];
                out[ZLP_OFF + (long)t * 8192 + r0 + tid] = s;
            }
        }
        FENCE();
        // no trailing barrier: next PH1 writes tH/scrZ only; C4 reads scrB/lpS;
        // PH2's scrB write is behind PH1's end-of-phase barrier.
    }
}

extern "C" void kernel_launch(void* const* d_in, const int* in_sizes, int n_in,
                              void* d_out, int out_size, void* d_ws, size_t ws_size,
                              hipStream_t stream)
{
    const float* input = (const float*)d_in[0];
    const float* eps   = (const float*)d_in[1];
    const float* u     = (const float*)d_in[2];
    const float* Wxh   = (const float*)d_in[3];
    const float* Wzh   = (const float*)d_in[4];
    const float* bh    = (const float*)d_in[5];
    const float* Wg    = (const float*)d_in[6];
    const float* bg    = (const float*)d_in[7];
    const float* Wp    = (const float*)d_in[8];
    const float* bp    = (const float*)d_in[9];
    const float* Wz    = (const float*)d_in[10];
    const float* bz    = (const float*)d_in[11];
    const float* Wsc   = (const float*)d_in[12];
    const float* bsc   = (const float*)d_in[13];
    const float* W1    = (const float*)d_in[14];
    const float* b1    = (const float*)d_in[15];
    const float* Wm    = (const float*)d_in[16];
    const float* bm    = (const float*)d_in[17];
    const float* Ws    = (const float*)d_in[18];
    const float* bs    = (const float*)d_in[19];
    const float* We1   = (const float*)d_in[20];
    const float* be1   = (const float*)d_in[21];
    const float* We2   = (const float*)d_in[22];
    const float* be2   = (const float*)d_in[23];

    u16* wa = (u16*)d_ws;   // ~1.45 MB used

    hipLaunchKernelGGL(prep_kernel, dim3(1408), dim3(256), 0, stream,
                       input, Wxh, Wzh, Wg, Wp, Wz, Wsc, W1, Wm, Ws, We1, We2, wa);

    hipLaunchKernelGGL(ssm_mfma_kernel, dim3(256), dim3(256), 0, stream,
                       eps, u, bh, bg, bp, bz, bsc, b1, bm, bs, be1, be2,
                       wa, (float*)d_out);
}